// Round 2
// baseline (262.710 us; speedup 1.0000x reference)
//
#include <hip/hip_runtime.h>
#include <cstdint>
#include <cstddef>

typedef _Float16 f16;
typedef __attribute__((ext_vector_type(4))) _Float16 f16x4;
typedef __attribute__((ext_vector_type(8))) _Float16 f16x8;
typedef __attribute__((ext_vector_type(4))) float f32x4;

static constexpr int BB = 4;
static constexpr int SS = 2048;
static constexpr int EE = 1024;

static constexpr int BM = 128, BN = 128;   // K handled as 2x32 buffers per barrier (legacy core)

// async global->LDS, 16B per lane. LDS dest must be wave-uniform base + lane*16.
__device__ __forceinline__ void gload_lds16(const f16* g, f16* l) {
  __builtin_amdgcn_global_load_lds(
      (const __attribute__((address_space(1))) void*)g,
      (__attribute__((address_space(3))) void*)l, 16, 0, 0);
}

struct Frag {
  int lane, wave, wy, wx, l16, quad, quadx;
  __device__ Frag() {
    const int tid = threadIdx.x;
    lane = tid & 63; wave = tid >> 6;
    wy = wave >> 1; wx = wave & 1;
    l16 = lane & 15; quad = lane >> 4;
    quadx = quad ^ ((l16 >> 2) & 3);   // XOR-swizzled chunk select
  }
};

// Staging swizzle: LDS chunk c holds global chunk (row=c>>2, kc=(c&3)^((c>>4)&3)).
// 128x32 f16 tile = 512 chunks of 16B; 2 chunks/thread.
struct Stager {
  const f16* g[2];
  int l[2];
  __device__ void init(const f16* base, int ld, const Frag& fr) {
#pragma unroll
    for (int i = 0; i < 2; ++i) {
      const int c = fr.wave * 128 + i * 64 + fr.lane;
      const int row = c >> 2;
      const int kcs = (c & 3) ^ ((c >> 4) & 3);
      g[i] = base + (size_t)row * ld + kcs * 8;
      l[i] = c * 8;
    }
  }
  __device__ __forceinline__ void stage(int ko, f16* lds) const {
    gload_lds16(g[0] + ko, lds + l[0]);
    gload_lds16(g[1] + ko, lds + l[1]);
  }
};

// One 16-MFMA round from a staged 128x32 buffer pair
__device__ __forceinline__ void mfma_round(
    const f16* __restrict__ Ash, const f16* __restrict__ Bsh,
    f32x4 acc[4][4], const Frag& fr)
{
  f16x8 af[4], bf[4];
#pragma unroll
  for (int mi = 0; mi < 4; ++mi)
    af[mi] = *(const f16x8*)(Ash + (fr.wy * 64 + mi * 16 + fr.l16) * 32 + fr.quadx * 8);
#pragma unroll
  for (int ni = 0; ni < 4; ++ni)
    bf[ni] = *(const f16x8*)(Bsh + (fr.wx * 64 + ni * 16 + fr.l16) * 32 + fr.quadx * 8);
#pragma unroll
  for (int mi = 0; mi < 4; ++mi)
#pragma unroll
    for (int ni = 0; ni < 4; ++ni)
      acc[mi][ni] = __builtin_amdgcn_mfma_f32_16x16x32_f16(af[mi], bf[ni], acc[mi][ni], 0, 0, 0);
}

// C[m,n] = sum_k A[m,k]*Bt[n,k]; 2x(128x32) staged per barrier -> 32 MFMA/barrier
__device__ __forceinline__ void gemm_core(
    const f16* __restrict__ A, const f16* __restrict__ Bt,
    int lda, int ldb, int kOuter,
    f16* __restrict__ Ash, f16* __restrict__ Bsh,   // each [2][128*32]
    f32x4 acc[4][4], const Frag& fr)
{
  Stager sa, sb;
  sa.init(A, lda, fr);
  sb.init(Bt, ldb, fr);
  for (int kt = 0; kt < kOuter; ++kt) {
    const int ko = kt * 64;
    sa.stage(ko, Ash);       sa.stage(ko + 32, Ash + 128 * 32);
    sb.stage(ko, Bsh);       sb.stage(ko + 32, Bsh + 128 * 32);
    __syncthreads();
    mfma_round(Ash, Bsh, acc, fr);
    mfma_round(Ash + 128 * 32, Bsh + 128 * 32, acc, fr);
    __syncthreads();
  }
}

// ---------------- single cast launch: X (2M f4) then Wq/Wk/Wv (256K f4 each) ----------------
__global__ __launch_bounds__(256) void cast_all_kernel(
    const float* __restrict__ xs,
    const float* __restrict__ w0, const float* __restrict__ w1, const float* __restrict__ w2,
    f16* __restrict__ Xh, f16* __restrict__ o0, f16* __restrict__ o1, f16* __restrict__ o2)
{
  const int i = blockIdx.x * 256 + threadIdx.x;   // f4 index < 2883584 (exact grid)
  const float* src; f16* dst; int idx;
  if (i < 2097152) {
    src = xs; dst = Xh; idx = i;
  } else {
    const int j = i - 2097152;
    const int w = j >> 18;          // 262144 f4 per weight matrix
    idx = j & 262143;
    src = (w == 0) ? w0 : (w == 1) ? w1 : w2;
    dst = (w == 0) ? o0 : (w == 1) ? o1 : o2;
  }
  const float4 f = ((const float4*)src)[idx];
  f16x4 h;
  h.x = (f16)f.x; h.y = (f16)f.y; h.z = (f16)f.z; h.w = (f16)f.w;
  ((f16x4*)dst)[idx] = h;
}

// ==================== deep-pipelined 256x128 projection GEMM ====================
// Grid of 768 blocks, 512 threads (8 waves as 4x2), LDS 96KB:
//   t in [0,256):   Q  = X[8192x1024] . Wq^T  (tile mt=u>>3 of 32, nt=u&7 of 8)
//   t in [256,512): K  = X . Wk^T
//   t in [512,768): Vt = Wv[1024x1024] . X^T  (tile mt=u>>6 of 4, nt=u&63 of 64)
// K=1024 as 16 tiles of BK=64. Per K-tile 4 phases, 8 MFMA each, counted vmcnt(3)
// once per tile (never 0 in steady state), raw s_barrier (no vmcnt-0 drain).
//
// LDS layout per tile buffer: rows x 8 chunks of 16B, chunk swizzle c' = c ^ (row&7)
// (breaks the 128B-row-stride full-wave bank collision on ds_read_b128).
// Half-tile slots: A-half h = rows [h*128, h*128+128); B-half h = rows [h*64, h*64+64).
// Read schedule (per wave, quadrants of acc[4][4]):
//   ph1: read a0(mi0-1),b0(ni0-1); MFMA q00    | stage A1(t+1) -> nxt
//   ph2: read b1(ni2-3);           MFMA q01    | stage B1(t+1) -> nxt
//   ph3: read a1(mi2-3);           MFMA q11    | stage B0(t+2) -> cur (B free after ph2)
//   ph4: (no reads);               MFMA q10    | stage A0(t+2) -> cur (A free after ph3)
// Tile-boundary wait vmcnt(3): newest 3 outstanding = B0(t+1)[1] + A0(t+1)[2]; forces
// A1/B1(t+1) (issued >= 2.5 phases earlier) to have landed. Stage-issues only target
// slots whose last reader completed >= 1 barrier+lgkmcnt(0) earlier -> race-free.

#define PBAR() asm volatile("s_barrier" ::: "memory")
#define LGKM0() do { asm volatile("s_waitcnt lgkmcnt(0)" ::: "memory"); \
                     __builtin_amdgcn_sched_barrier(0); } while (0)

__global__ __launch_bounds__(512, 1) void proj2_kernel(
    const f16* __restrict__ X,
    const f16* __restrict__ Wq, const f16* __restrict__ Wk, const f16* __restrict__ Wv,
    const float* __restrict__ bq, const float* __restrict__ bk, const float* __restrict__ bv,
    f16* __restrict__ Qh, f16* __restrict__ Kh, f16* __restrict__ Vt)
{
  __shared__ __align__(16) f16 smem[49152];   // A: 2x16384 f16 (64KB), B: 2x8192 f16 (32KB)
  const int tid = threadIdx.x;
  const int lane = tid & 63, wave = tid >> 6;
  const int wy = wave >> 1, wx = wave & 1;    // 4x2 waves -> per-wave 64x64 output
  const int l16 = lane & 15, quad = lane >> 4;

  const int t = blockIdx.x;
  const int which = t >> 8;                   // 0=Q, 1=K, 2=V
  const int u = t & 255;
  const f16* Abase; const f16* Bbase;
  int mt, nt;
  if (which < 2) {
    mt = u >> 3; nt = u & 7;
    Abase = X + (size_t)mt * 256 * EE;
    Bbase = ((which == 0) ? Wq : Wk) + (size_t)nt * 128 * EE;
  } else {
    mt = u >> 6; nt = u & 63;
    Abase = Wv + (size_t)mt * 256 * EE;
    Bbase = X + (size_t)nt * 128 * EE;
  }

  // ---- staging descriptors: 6 roles (A-half0 j0/j1, A-half1 j0/j1, B-half0, B-half1)
  const f16* gA[4]; int lA[4];
  const f16* gB[2]; int lB[2];
#pragma unroll
  for (int h = 0; h < 2; ++h) {
#pragma unroll
    for (int j = 0; j < 2; ++j) {
      const int slot = h * 1024 + wave * 128 + j * 64 + lane;   // A tile: 2048 slots
      const int r = slot >> 3, cg = (slot & 7) ^ (r & 7);
      gA[h * 2 + j] = Abase + (size_t)r * EE + cg * 8;
      lA[h * 2 + j] = slot * 8;
    }
    const int slot = h * 512 + wave * 64 + lane;                // B tile: 1024 slots
    const int r = slot >> 3, cg = (slot & 7) ^ (r & 7);
    gB[h] = Bbase + (size_t)r * EE + cg * 8;
    lB[h] = slot * 8;
  }

  // LDS buffer bases by integer offset only (no LDS pointer arrays — addrspacecast
  // static initializers don't compile on gfx950).
  auto stA = [&](int buf, int h, int kt) {
    const int ko = kt * 64;
    f16* base = smem + buf * 16384;
    gload_lds16(gA[h * 2 + 0] + ko, base + lA[h * 2 + 0]);
    gload_lds16(gA[h * 2 + 1] + ko, base + lA[h * 2 + 1]);
  };
  auto stB = [&](int buf, int h, int kt) {
    f16* base = smem + 32768 + buf * 8192;
    gload_lds16(gB[h] + kt * 64, base + lB[h]);
  };

  // ---- loop-invariant LDS read offsets (f16 units), swizzled
  int offA[4][2], offB[4][2];
#pragma unroll
  for (int i = 0; i < 4; ++i)
#pragma unroll
    for (int ks = 0; ks < 2; ++ks) {
      { const int row = wy * 64 + i * 16 + l16, c = ks * 4 + quad;
        offA[i][ks] = (row * 8 + (c ^ (row & 7))) * 8; }
      { const int row = wx * 64 + i * 16 + l16, c = ks * 4 + quad;
        offB[i][ks] = (row * 8 + (c ^ (row & 7))) * 8; }
    }

  // ---- prologue: tile0 fully (A0,A1,B0,B1), then B0(1), A0(1). Issue order matters.
  stA(0, 0, 0); stA(0, 1, 0); stB(0, 0, 0); stB(0, 1, 0);
  stB(1, 0, 1); stA(1, 0, 1);

  f32x4 acc[4][4] = {};

  constexpr int NT = 16;   // 1024 / 64
  for (int kt = 0; kt < NT; ++kt) {
    const int cur = kt & 1, nxt = cur ^ 1;
    // tile-boundary wait: steady state leaves the 3 newest loads (B0,A0 of kt+1) in flight
    if (kt == NT - 1) asm volatile("s_waitcnt vmcnt(0)" ::: "memory");
    else              asm volatile("s_waitcnt vmcnt(3)" ::: "memory");
    PBAR();
    const f16* Ac = smem + cur * 16384;
    const f16* Bc = smem + 32768 + cur * 8192;
    f16x8 a0[2][2], a1[2][2], b0[2][2], b1[2][2];

    // ---- phase 1: read a0,b0 ; stage A1(kt+1) ; MFMA quadrant (mi0-1, ni0-1)
#pragma unroll
    for (int mi = 0; mi < 2; ++mi)
#pragma unroll
      for (int ks = 0; ks < 2; ++ks) a0[mi][ks] = *(const f16x8*)(Ac + offA[mi][ks]);
#pragma unroll
    for (int ni = 0; ni < 2; ++ni)
#pragma unroll
      for (int ks = 0; ks < 2; ++ks) b0[ni][ks] = *(const f16x8*)(Bc + offB[ni][ks]);
    if (kt + 1 < NT) stA(nxt, 1, kt + 1);
    PBAR(); LGKM0();
    __builtin_amdgcn_s_setprio(1);
#pragma unroll
    for (int mi = 0; mi < 2; ++mi)
#pragma unroll
      for (int ni = 0; ni < 2; ++ni)
#pragma unroll
        for (int ks = 0; ks < 2; ++ks)
          acc[mi][ni] = __builtin_amdgcn_mfma_f32_16x16x32_f16(a0[mi][ks], b0[ni][ks], acc[mi][ni], 0, 0, 0);
    __builtin_amdgcn_s_setprio(0);
    PBAR();

    // ---- phase 2: read b1 ; stage B1(kt+1) ; MFMA quadrant (mi0-1, ni2-3)
#pragma unroll
    for (int ni = 0; ni < 2; ++ni)
#pragma unroll
      for (int ks = 0; ks < 2; ++ks) b1[ni][ks] = *(const f16x8*)(Bc + offB[ni + 2][ks]);
    if (kt + 1 < NT) stB(nxt, 1, kt + 1);
    PBAR(); LGKM0();
    __builtin_amdgcn_s_setprio(1);
#pragma unroll
    for (int mi = 0; mi < 2; ++mi)
#pragma unroll
      for (int ni = 0; ni < 2; ++ni)
#pragma unroll
        for (int ks = 0; ks < 2; ++ks)
          acc[mi][ni + 2] = __builtin_amdgcn_mfma_f32_16x16x32_f16(a0[mi][ks], b1[ni][ks], acc[mi][ni + 2], 0, 0, 0);
    __builtin_amdgcn_s_setprio(0);
    PBAR();

    // ---- phase 3: read a1 ; stage B0(kt+2) into cur (B slots free after ph2) ; MFMA (mi2-3, ni2-3)
#pragma unroll
    for (int mi = 0; mi < 2; ++mi)
#pragma unroll
      for (int ks = 0; ks < 2; ++ks) a1[mi][ks] = *(const f16x8*)(Ac + offA[mi + 2][ks]);
    if (kt + 2 < NT) stB(cur, 0, kt + 2);
    PBAR(); LGKM0();
    __builtin_amdgcn_s_setprio(1);
#pragma unroll
    for (int mi = 0; mi < 2; ++mi)
#pragma unroll
      for (int ni = 0; ni < 2; ++ni)
#pragma unroll
        for (int ks = 0; ks < 2; ++ks)
          acc[mi + 2][ni + 2] = __builtin_amdgcn_mfma_f32_16x16x32_f16(a1[mi][ks], b1[ni][ks], acc[mi + 2][ni + 2], 0, 0, 0);
    __builtin_amdgcn_s_setprio(0);
    PBAR();

    // ---- phase 4: stage A0(kt+2) into cur (A slots free after ph3) ; MFMA (mi2-3, ni0-1)
    if (kt + 2 < NT) stA(cur, 0, kt + 2);
    __builtin_amdgcn_s_setprio(1);
#pragma unroll
    for (int mi = 0; mi < 2; ++mi)
#pragma unroll
      for (int ni = 0; ni < 2; ++ni)
#pragma unroll
        for (int ks = 0; ks < 2; ++ks)
          acc[mi + 2][ni] = __builtin_amdgcn_mfma_f32_16x16x32_f16(a1[mi][ks], b0[ni][ks], acc[mi + 2][ni], 0, 0, 0);
    __builtin_amdgcn_s_setprio(0);
    // loop-top vmcnt+barrier of next tile closes this tile
  }

  // ---- epilogue (all loads drained at kt=NT-1 top)
  const int r0 = mt * 256 + wy * 64;
  const int c0 = nt * 128 + wx * 64;
  if (which < 2) {
    const float* bias = (which == 0) ? bq : bk;
    f16* out = (which == 0) ? Qh : Kh;
#pragma unroll
    for (int ni = 0; ni < 4; ++ni) {
      const int c = c0 + ni * 16 + l16;
      const float bz = bias[c];
#pragma unroll
      for (int mi = 0; mi < 4; ++mi) {
        const int r = r0 + mi * 16 + quad * 4;
#pragma unroll
        for (int i = 0; i < 4; ++i)
          out[(size_t)(r + i) * EE + c] = (f16)(acc[mi][ni][i] + bz);
      }
    }
  } else {
#pragma unroll
    for (int ni = 0; ni < 4; ++ni) {
      const int cg = c0 + ni * 16 + l16;        // global s in [0, 8192)
      const int b = cg >> 11, sc = cg & 2047;
      f16* out = Vt + (size_t)b * EE * SS;
#pragma unroll
      for (int mi = 0; mi < 4; ++mi) {
        const int r = r0 + mi * 16 + quad * 4;  // e row
#pragma unroll
        for (int i = 0; i < 4; ++i)
          out[(size_t)(r + i) * SS + sc] = (f16)(acc[mi][ni][i] + bv[r + i]);
      }
    }
  }
}

// ---------------- scores: Sc[q,k] = (Q[q,:] . K[k,:]) / 32, lower-tri tiles only ----------------
__global__ __launch_bounds__(256) void scores_kernel(
    const f16* __restrict__ Q, const f16* __restrict__ Kh, f16* __restrict__ Sc)
{
  __shared__ __align__(16) f16 Ash[2][BM * 32];
  __shared__ __align__(16) f16 Bsh[2][BN * 32];
  const int t = blockIdx.x, b = blockIdx.z;
  int qt = 0;
  while ((qt + 1) * (qt + 2) / 2 <= t) ++qt;
  const int kt = t - qt * (qt + 1) / 2;
  const f16* A  = Q  + (size_t)b * SS * EE + (size_t)qt * BM * EE;
  const f16* Bp = Kh + (size_t)b * SS * EE + (size_t)kt * BN * EE;
  f16* out = Sc + (size_t)b * SS * SS;
  Frag fr;
  f32x4 acc[4][4] = {};
  gemm_core(A, Bp, EE, EE, EE / 64, Ash[0], Bsh[0], acc, fr);
  const float scale = 0.03125f;   // 1/sqrt(1024)
#pragma unroll
  for (int ni = 0; ni < 4; ++ni) {
    const int c = kt * BN + fr.wx * 64 + ni * 16 + fr.l16;
#pragma unroll
    for (int mi = 0; mi < 4; ++mi) {
      const int r = qt * BM + fr.wy * 64 + mi * 16 + fr.quad * 4;
#pragma unroll
      for (int i = 0; i < 4; ++i)
        out[(size_t)(r + i) * SS + c] = (f16)(acc[mi][ni][i] * scale);
    }
  }
}

// ---------------- in-place causal softmax over row q (vectorized f16x8) ----------------
__global__ __launch_bounds__(256) void softmax_kernel(f16* __restrict__ Sc)
{
  const int q = blockIdx.x, b = blockIdx.y;
  f16* row = Sc + (size_t)b * SS * SS + (size_t)q * SS;
  const int n = q + 1;
  const int kend = ((q >> 7) + 1) << 7;   // PV reads K up to this 128-boundary
  const int tid = threadIdx.x;
  const int i0 = tid * 8;

  float v[8];
  if (i0 + 8 <= n) {
    const f16x8 h = *(const f16x8*)(row + i0);
#pragma unroll
    for (int j = 0; j < 8; ++j) v[j] = (float)h[j];
  } else {
#pragma unroll
    for (int j = 0; j < 8; ++j) {
      const int idx = i0 + j;
      v[j] = (idx < n) ? (float)row[idx] : -1e30f;
    }
  }

  float m = v[0];
#pragma unroll
  for (int j = 1; j < 8; ++j) m = fmaxf(m, v[j]);
  __shared__ float red[4];
#pragma unroll
  for (int off = 32; off > 0; off >>= 1) m = fmaxf(m, __shfl_down(m, off));
  if ((tid & 63) == 0) red[tid >> 6] = m;
  __syncthreads();
  m = fmaxf(fmaxf(red[0], red[1]), fmaxf(red[2], red[3]));

  float sum = 0.f;
#pragma unroll
  for (int j = 0; j < 8; ++j) {
    v[j] = (i0 + j < n) ? __expf(v[j] - m) : 0.f;
    sum += v[j];
  }
#pragma unroll
  for (int off = 32; off > 0; off >>= 1) sum += __shfl_down(sum, off);
  __syncthreads();
  if ((tid & 63) == 0) red[tid >> 6] = sum;
  __syncthreads();
  sum = red[0] + red[1] + red[2] + red[3];
  const float inv = 1.f / sum;

  if (i0 < kend) {
    f16x8 h;
#pragma unroll
    for (int j = 0; j < 8; ++j) h[j] = (f16)(v[j] * inv);   // v==0 beyond n
    *(f16x8*)(row + i0) = h;
  }
}

// ---------------- PV: Y[q,e] = sum_{k<=q} P[q,k] * Vt[e,k], fp32 out ----------------
// Flat 512-block grid with complementary-pair remap: block t and t+256 map to
// qt=15-qh and qt=qh (same et,b) -> uniform per-CU K-tile load.
__global__ __launch_bounds__(256) void pv_kernel(
    const f16* __restrict__ P, const f16* __restrict__ Vt, float* __restrict__ Y)
{
  __shared__ __align__(16) f16 Ash[2][BM * 32];
  __shared__ __align__(16) f16 Bsh[2][BN * 32];
  const int t = blockIdx.x;
  const int u = t & 255;
  const int qh = u & 7, et = (u >> 3) & 7, b = u >> 6;
  const int qt = (t < 256) ? (15 - qh) : qh;
  const f16* A  = P  + (size_t)b * SS * SS + (size_t)qt * BM * SS;
  const f16* Bp = Vt + (size_t)b * EE * SS + (size_t)et * BN * SS;
  float* out = Y + (size_t)b * SS * EE;
  Frag fr;
  f32x4 acc[4][4] = {};
  gemm_core(A, Bp, SS, SS, (qt + 1) * 2, Ash[0], Bsh[0], acc, fr);
#pragma unroll
  for (int ni = 0; ni < 4; ++ni) {
    const int c = et * BN + fr.wx * 64 + ni * 16 + fr.l16;
#pragma unroll
    for (int mi = 0; mi < 4; ++mi) {
      const int r = qt * BM + fr.wy * 64 + mi * 16 + fr.quad * 4;
#pragma unroll
      for (int i = 0; i < 4; ++i)
        out[(size_t)(r + i) * EE + c] = acc[mi][ni][i];
    }
  }
}

extern "C" void kernel_launch(void* const* d_in, const int* in_sizes, int n_in,
                              void* d_out, int out_size, void* d_ws, size_t ws_size,
                              hipStream_t stream)
{
  const float* xs  = (const float*)d_in[0];
  const float* WQw = (const float*)d_in[1];
  const float* WQb = (const float*)d_in[2];
  const float* WKw = (const float*)d_in[3];
  const float* WKb = (const float*)d_in[4];
  const float* WVw = (const float*)d_in[5];
  const float* WVb = (const float*)d_in[6];

  const size_t ME = (size_t)BB * SS * EE;   // 8M tokens*dim
  const size_t WE = (size_t)EE * EE;        // 1M weight elems

  f16* Xh = (f16*)d_ws;
  f16* Wq = Xh + ME;
  f16* Wk = Wq + WE;
  f16* Wv = Wk + WE;
  f16* Qh = Wv + WE;
  f16* Kh = Qh + ME;
  f16* Vt = Kh + ME;
  f16* Sc = Vt + ME;   // BB*SS*SS f16 = 32 MiB

  // 1) casts (one launch): (8M + 3*1M)/4 = 2883584 f4 -> 11264 blocks exact
  cast_all_kernel<<<dim3(11264), 256, 0, stream>>>(
      xs, WQw, WKw, WVw, Xh, Wq, Wk, Wv);

  // 2) projections: deep-pipelined 256x128 tiles; 768 blocks = exactly 3 CU rounds
  proj2_kernel<<<dim3(768), 512, 0, stream>>>(
      Xh, Wq, Wk, Wv, WQb, WKb, WVb, Qh, Kh, Vt);

  // 3) scores (lower-tri tiles)
  const int nTri = (SS / BM) * (SS / BM + 1) / 2;   // 136
  scores_kernel<<<dim3(nTri, 1, BB), 256, 0, stream>>>(Qh, Kh, Sc);

  // 4) softmax
  softmax_kernel<<<dim3(SS, BB), 256, 0, stream>>>(Sc);

  // 5) PV
  pv_kernel<<<dim3(512), 256, 0, stream>>>(Sc, Vt, (float*)d_out);
}

// Round 3
// 255.562 us; speedup vs baseline: 1.0280x; 1.0280x over previous
//
#include <hip/hip_runtime.h>
#include <cstdint>
#include <cstddef>

typedef _Float16 f16;
typedef __attribute__((ext_vector_type(4))) _Float16 f16x4;
typedef __attribute__((ext_vector_type(8))) _Float16 f16x8;
typedef __attribute__((ext_vector_type(4))) float f32x4;

static constexpr int BB = 4;
static constexpr int SS = 2048;
static constexpr int EE = 1024;

static constexpr int BM = 128, BN = 128;   // legacy core tile (scores/pv)

// async global->LDS, 16B per lane. LDS dest must be wave-uniform base + lane*16.
__device__ __forceinline__ void gload_lds16(const f16* g, f16* l) {
  __builtin_amdgcn_global_load_lds(
      (const __attribute__((address_space(1))) void*)g,
      (__attribute__((address_space(3))) void*)l, 16, 0, 0);
}

struct Frag {
  int lane, wave, wy, wx, l16, quad, quadx;
  __device__ Frag() {
    const int tid = threadIdx.x;
    lane = tid & 63; wave = tid >> 6;
    wy = wave >> 1; wx = wave & 1;
    l16 = lane & 15; quad = lane >> 4;
    quadx = quad ^ ((l16 >> 2) & 3);   // XOR-swizzled chunk select
  }
};

// Staging swizzle: LDS chunk c holds global chunk (row=c>>2, kc=(c&3)^((c>>4)&3)).
// 128x32 f16 tile = 512 chunks of 16B; 2 chunks/thread.
struct Stager {
  const f16* g[2];
  int l[2];
  __device__ void init(const f16* base, int ld, const Frag& fr) {
#pragma unroll
    for (int i = 0; i < 2; ++i) {
      const int c = fr.wave * 128 + i * 64 + fr.lane;
      const int row = c >> 2;
      const int kcs = (c & 3) ^ ((c >> 4) & 3);
      g[i] = base + (size_t)row * ld + kcs * 8;
      l[i] = c * 8;
    }
  }
  __device__ __forceinline__ void stage(int ko, f16* lds) const {
    gload_lds16(g[0] + ko, lds + l[0]);
    gload_lds16(g[1] + ko, lds + l[1]);
  }
};

// One 16-MFMA round from a staged 128x32 buffer pair
__device__ __forceinline__ void mfma_round(
    const f16* __restrict__ Ash, const f16* __restrict__ Bsh,
    f32x4 acc[4][4], const Frag& fr)
{
  f16x8 af[4], bf[4];
#pragma unroll
  for (int mi = 0; mi < 4; ++mi)
    af[mi] = *(const f16x8*)(Ash + (fr.wy * 64 + mi * 16 + fr.l16) * 32 + fr.quadx * 8);
#pragma unroll
  for (int ni = 0; ni < 4; ++ni)
    bf[ni] = *(const f16x8*)(Bsh + (fr.wx * 64 + ni * 16 + fr.l16) * 32 + fr.quadx * 8);
#pragma unroll
  for (int mi = 0; mi < 4; ++mi)
#pragma unroll
    for (int ni = 0; ni < 4; ++ni)
      acc[mi][ni] = __builtin_amdgcn_mfma_f32_16x16x32_f16(af[mi], bf[ni], acc[mi][ni], 0, 0, 0);
}

// C[m,n] = sum_k A[m,k]*Bt[n,k]; 2x(128x32) staged per barrier -> 32 MFMA/barrier
__device__ __forceinline__ void gemm_core(
    const f16* __restrict__ A, const f16* __restrict__ Bt,
    int lda, int ldb, int kOuter,
    f16* __restrict__ Ash, f16* __restrict__ Bsh,   // each [2][128*32]
    f32x4 acc[4][4], const Frag& fr)
{
  Stager sa, sb;
  sa.init(A, lda, fr);
  sb.init(Bt, ldb, fr);
  for (int kt = 0; kt < kOuter; ++kt) {
    const int ko = kt * 64;
    sa.stage(ko, Ash);       sa.stage(ko + 32, Ash + 128 * 32);
    sb.stage(ko, Bsh);       sb.stage(ko + 32, Bsh + 128 * 32);
    __syncthreads();
    mfma_round(Ash, Bsh, acc, fr);
    mfma_round(Ash + 128 * 32, Bsh + 128 * 32, acc, fr);
    __syncthreads();
  }
}

// ---------------- single cast launch: X (2M f4) then Wq/Wk/Wv (256K f4 each) ----------------
__global__ __launch_bounds__(256) void cast_all_kernel(
    const float* __restrict__ xs,
    const float* __restrict__ w0, const float* __restrict__ w1, const float* __restrict__ w2,
    f16* __restrict__ Xh, f16* __restrict__ o0, f16* __restrict__ o1, f16* __restrict__ o2)
{
  const int i = blockIdx.x * 256 + threadIdx.x;   // f4 index < 2883584 (exact grid)
  const float* src; f16* dst; int idx;
  if (i < 2097152) {
    src = xs; dst = Xh; idx = i;
  } else {
    const int j = i - 2097152;
    const int w = j >> 18;          // 262144 f4 per weight matrix
    idx = j & 262143;
    src = (w == 0) ? w0 : (w == 1) ? w1 : w2;
    dst = (w == 0) ? o0 : (w == 1) ? o1 : o2;
  }
  const float4 f = ((const float4*)src)[idx];
  f16x4 h;
  h.x = (f16)f.x; h.y = (f16)f.y; h.z = (f16)f.z; h.w = (f16)f.w;
  ((f16x4*)dst)[idx] = h;
}

// ==================== proj3: 256x128 tiles, 3-deep LDS ring, 2 barriers/K-tile ====================
// Grid 768 blocks, 512 threads (8 waves 4x2), LDS 144KB (3 x (A 32KB + B 16KB)).
// Per K-tile kt:
//   PBAR                       // all waves done reading buf[(kt+2)%3] (tile kt-1)
//   stage full tile kt+2 -> buf[(kt+2)%3]   (6 gload_lds/thread: A 4, B 2)
//   s_waitcnt vmcnt(12)        // drain tile kt's 6 loads (2-tile flight time), keep kt+1/kt+2
//   PBAR                       // joint: ALL waves' tile-kt loads landed (vmcnt BEFORE barrier)
//   16 ds_read_b128 (ks0 then ks1) ; 32 MFMA (compiler-scheduled lgkm interleave)
// XCD-aware index map: blocks sharing the 512KB A-tile map to the same XCD (t&7).
__global__ __launch_bounds__(512, 1) void proj3_kernel(
    const f16* __restrict__ X,
    const f16* __restrict__ Wq, const f16* __restrict__ Wk, const f16* __restrict__ Wv,
    const float* __restrict__ bq, const float* __restrict__ bk, const float* __restrict__ bv,
    f16* __restrict__ Qh, f16* __restrict__ Kh, f16* __restrict__ Vt)
{
  __shared__ __align__(16) f16 smem[73728];   // A: 3x16384 f16, B: 3x8192 f16 = 144KB
  const int tid = threadIdx.x;
  const int lane = tid & 63, wave = tid >> 6;
  const int wy = wave >> 1, wx = wave & 1;    // 4x2 waves -> per-wave 64x64 output
  const int l16 = lane & 15, quad = lane >> 4;

  const int t = blockIdx.x;
  const int which = t >> 8;                   // 0=Q, 1=K, 2=V
  const int u = t & 255;
  const int c8 = u & 7, g = u >> 3;           // c8 = XCD under round-robin
  const f16* Abase; const f16* Bbase;
  int mt, nt;
  if (which < 2) {
    mt = c8 + 8 * (g >> 3);                   // blocks sharing mt -> same XCD
    nt = g & 7;
    Abase = X + (size_t)mt * 256 * EE;
    Bbase = ((which == 0) ? Wq : Wk) + (size_t)nt * 128 * EE;
  } else {
    mt = g & 3;                               // blocks sharing nt (X-tile) -> same XCD
    nt = c8 + 8 * (g >> 2);
    Abase = Wv + (size_t)mt * 256 * EE;
    Bbase = X + (size_t)nt * 128 * EE;
  }

  // ---- staging descriptors: full tile = A 2048 chunks (4/thread) + B 1024 (2/thread)
  const f16* gA[4]; int lA[4];
  const f16* gB[2]; int lB[2];
#pragma unroll
  for (int j = 0; j < 4; ++j) {
    const int slot = j * 512 + tid;
    const int r = slot >> 3, cg = (slot & 7) ^ (r & 7);
    gA[j] = Abase + (size_t)r * EE + cg * 8;
    lA[j] = slot * 8;
  }
#pragma unroll
  for (int j = 0; j < 2; ++j) {
    const int slot = j * 512 + tid;
    const int r = slot >> 3, cg = (slot & 7) ^ (r & 7);
    gB[j] = Bbase + (size_t)r * EE + cg * 8;
    lB[j] = slot * 8;
  }

  auto stageTile = [&](int bi, int kt) {
    const int ko = kt * 64;
    f16* ab = smem + bi * 16384;
    f16* bb = smem + 49152 + bi * 8192;
    gload_lds16(gA[0] + ko, ab + lA[0]);
    gload_lds16(gA[1] + ko, ab + lA[1]);
    gload_lds16(gA[2] + ko, ab + lA[2]);
    gload_lds16(gA[3] + ko, ab + lA[3]);
    gload_lds16(gB[0] + ko, bb + lB[0]);
    gload_lds16(gB[1] + ko, bb + lB[1]);
  };

  // ---- loop-invariant LDS read offsets (f16 units), swizzled
  int offA[4][2], offB[4][2];
#pragma unroll
  for (int i = 0; i < 4; ++i)
#pragma unroll
    for (int ks = 0; ks < 2; ++ks) {
      { const int row = wy * 64 + i * 16 + l16, c = ks * 4 + quad;
        offA[i][ks] = (row * 8 + (c ^ (row & 7))) * 8; }
      { const int row = wx * 64 + i * 16 + l16, c = ks * 4 + quad;
        offB[i][ks] = (row * 8 + (c ^ (row & 7))) * 8; }
    }

  // ---- prologue: tiles 0,1 staged into bufs 0,1
  stageTile(0, 0);
  stageTile(1, 1);

  f32x4 acc[4][4] = {};

  constexpr int NT = 16;   // 1024 / 64
  int bi = 0;              // buffer of tile kt
  for (int kt = 0; kt < NT; ++kt) {
    const int bs = (bi >= 1) ? bi - 1 : bi + 2;    // (bi+2)%3 — buffer of tile kt+2
    __builtin_amdgcn_s_barrier();                   // buf bs fully consumed (tile kt-1)
    if (kt <= NT - 3) stageTile(bs, kt + 2);
    if (kt <= NT - 3)      asm volatile("s_waitcnt vmcnt(12)" ::: "memory");
    else if (kt == NT - 2) asm volatile("s_waitcnt vmcnt(6)" ::: "memory");
    else                   asm volatile("s_waitcnt vmcnt(0)" ::: "memory");
    __builtin_amdgcn_s_barrier();                   // all waves' tile-kt loads landed

    const f16* Ac = smem + bi * 16384;
    const f16* Bc = smem + 49152 + bi * 8192;
    f16x8 a[4][2], b[4][2];
    // ks0 reads first, then ks1 — lets compiler start ks0 MFMAs while ks1 in flight
#pragma unroll
    for (int mi = 0; mi < 4; ++mi) a[mi][0] = *(const f16x8*)(Ac + offA[mi][0]);
#pragma unroll
    for (int ni = 0; ni < 4; ++ni) b[ni][0] = *(const f16x8*)(Bc + offB[ni][0]);
#pragma unroll
    for (int mi = 0; mi < 4; ++mi) a[mi][1] = *(const f16x8*)(Ac + offA[mi][1]);
#pragma unroll
    for (int ni = 0; ni < 4; ++ni) b[ni][1] = *(const f16x8*)(Bc + offB[ni][1]);

    __builtin_amdgcn_s_setprio(1);
#pragma unroll
    for (int mi = 0; mi < 4; ++mi)
#pragma unroll
      for (int ni = 0; ni < 4; ++ni)
        acc[mi][ni] = __builtin_amdgcn_mfma_f32_16x16x32_f16(a[mi][0], b[ni][0], acc[mi][ni], 0, 0, 0);
#pragma unroll
    for (int mi = 0; mi < 4; ++mi)
#pragma unroll
      for (int ni = 0; ni < 4; ++ni)
        acc[mi][ni] = __builtin_amdgcn_mfma_f32_16x16x32_f16(a[mi][1], b[ni][1], acc[mi][ni], 0, 0, 0);
    __builtin_amdgcn_s_setprio(0);

    bi = (bi == 2) ? 0 : bi + 1;
  }

  // ---- epilogue (all loads drained at kt=NT-1; own reads complete per-wave)
  const int r0 = mt * 256 + wy * 64;
  const int c0 = nt * 128 + wx * 64;
  if (which < 2) {
    const float* bias = (which == 0) ? bq : bk;
    f16* out = (which == 0) ? Qh : Kh;
#pragma unroll
    for (int ni = 0; ni < 4; ++ni) {
      const int c = c0 + ni * 16 + l16;
      const float bz = bias[c];
#pragma unroll
      for (int mi = 0; mi < 4; ++mi) {
        const int r = r0 + mi * 16 + quad * 4;
#pragma unroll
        for (int i = 0; i < 4; ++i)
          out[(size_t)(r + i) * EE + c] = (f16)(acc[mi][ni][i] + bz);
      }
    }
  } else {
#pragma unroll
    for (int ni = 0; ni < 4; ++ni) {
      const int cg = c0 + ni * 16 + l16;        // global s in [0, 8192)
      const int b = cg >> 11, sc = cg & 2047;
      f16* out = Vt + (size_t)b * EE * SS;
#pragma unroll
      for (int mi = 0; mi < 4; ++mi) {
        const int r = r0 + mi * 16 + quad * 4;  // e row
#pragma unroll
        for (int i = 0; i < 4; ++i)
          out[(size_t)(r + i) * SS + sc] = (f16)(acc[mi][ni][i] + bv[r + i]);
      }
    }
  }
}

// ---------------- scores: Sc[q,k] = (Q[q,:] . K[k,:]) / 32, lower-tri tiles only ----------------
__global__ __launch_bounds__(256) void scores_kernel(
    const f16* __restrict__ Q, const f16* __restrict__ Kh, f16* __restrict__ Sc)
{
  __shared__ __align__(16) f16 Ash[2][BM * 32];
  __shared__ __align__(16) f16 Bsh[2][BN * 32];
  const int t = blockIdx.x, b = blockIdx.z;
  int qt = 0;
  while ((qt + 1) * (qt + 2) / 2 <= t) ++qt;
  const int kt = t - qt * (qt + 1) / 2;
  const f16* A  = Q  + (size_t)b * SS * EE + (size_t)qt * BM * EE;
  const f16* Bp = Kh + (size_t)b * SS * EE + (size_t)kt * BN * EE;
  f16* out = Sc + (size_t)b * SS * SS;
  Frag fr;
  f32x4 acc[4][4] = {};
  gemm_core(A, Bp, EE, EE, EE / 64, Ash[0], Bsh[0], acc, fr);
  const float scale = 0.03125f;   // 1/sqrt(1024)
#pragma unroll
  for (int ni = 0; ni < 4; ++ni) {
    const int c = kt * BN + fr.wx * 64 + ni * 16 + fr.l16;
#pragma unroll
    for (int mi = 0; mi < 4; ++mi) {
      const int r = qt * BM + fr.wy * 64 + mi * 16 + fr.quad * 4;
#pragma unroll
      for (int i = 0; i < 4; ++i)
        out[(size_t)(r + i) * SS + c] = (f16)(acc[mi][ni][i] * scale);
    }
  }
}

// ---------------- in-place causal softmax over row q (vectorized f16x8) ----------------
__global__ __launch_bounds__(256) void softmax_kernel(f16* __restrict__ Sc)
{
  const int q = blockIdx.x, b = blockIdx.y;
  f16* row = Sc + (size_t)b * SS * SS + (size_t)q * SS;
  const int n = q + 1;
  const int kend = ((q >> 7) + 1) << 7;   // PV reads K up to this 128-boundary
  const int tid = threadIdx.x;
  const int i0 = tid * 8;

  float v[8];
  if (i0 + 8 <= n) {
    const f16x8 h = *(const f16x8*)(row + i0);
#pragma unroll
    for (int j = 0; j < 8; ++j) v[j] = (float)h[j];
  } else {
#pragma unroll
    for (int j = 0; j < 8; ++j) {
      const int idx = i0 + j;
      v[j] = (idx < n) ? (float)row[idx] : -1e30f;
    }
  }

  float m = v[0];
#pragma unroll
  for (int j = 1; j < 8; ++j) m = fmaxf(m, v[j]);
  __shared__ float red[4];
#pragma unroll
  for (int off = 32; off > 0; off >>= 1) m = fmaxf(m, __shfl_down(m, off));
  if ((tid & 63) == 0) red[tid >> 6] = m;
  __syncthreads();
  m = fmaxf(fmaxf(red[0], red[1]), fmaxf(red[2], red[3]));

  float sum = 0.f;
#pragma unroll
  for (int j = 0; j < 8; ++j) {
    v[j] = (i0 + j < n) ? __expf(v[j] - m) : 0.f;
    sum += v[j];
  }
#pragma unroll
  for (int off = 32; off > 0; off >>= 1) sum += __shfl_down(sum, off);
  __syncthreads();
  if ((tid & 63) == 0) red[tid >> 6] = sum;
  __syncthreads();
  sum = red[0] + red[1] + red[2] + red[3];
  const float inv = 1.f / sum;

  if (i0 < kend) {
    f16x8 h;
#pragma unroll
    for (int j = 0; j < 8; ++j) h[j] = (f16)(v[j] * inv);   // v==0 beyond n
    *(f16x8*)(row + i0) = h;
  }
}

// ---------------- PV: Y[q,e] = sum_{k<=q} P[q,k] * Vt[e,k], fp32 out ----------------
// Flat 512-block grid with complementary-pair remap: block t and t+256 map to
// qt=15-qh and qt=qh (same et,b) -> uniform per-CU K-tile load.
__global__ __launch_bounds__(256) void pv_kernel(
    const f16* __restrict__ P, const f16* __restrict__ Vt, float* __restrict__ Y)
{
  __shared__ __align__(16) f16 Ash[2][BM * 32];
  __shared__ __align__(16) f16 Bsh[2][BN * 32];
  const int t = blockIdx.x;
  const int u = t & 255;
  const int qh = u & 7, et = (u >> 3) & 7, b = u >> 6;
  const int qt = (t < 256) ? (15 - qh) : qh;
  const f16* A  = P  + (size_t)b * SS * SS + (size_t)qt * BM * SS;
  const f16* Bp = Vt + (size_t)b * EE * SS + (size_t)et * BN * SS;
  float* out = Y + (size_t)b * SS * EE;
  Frag fr;
  f32x4 acc[4][4] = {};
  gemm_core(A, Bp, SS, SS, (qt + 1) * 2, Ash[0], Bsh[0], acc, fr);
#pragma unroll
  for (int ni = 0; ni < 4; ++ni) {
    const int c = et * BN + fr.wx * 64 + ni * 16 + fr.l16;
#pragma unroll
    for (int mi = 0; mi < 4; ++mi) {
      const int r = qt * BM + fr.wy * 64 + mi * 16 + fr.quad * 4;
#pragma unroll
      for (int i = 0; i < 4; ++i)
        out[(size_t)(r + i) * EE + c] = acc[mi][ni][i];
    }
  }
}

extern "C" void kernel_launch(void* const* d_in, const int* in_sizes, int n_in,
                              void* d_out, int out_size, void* d_ws, size_t ws_size,
                              hipStream_t stream)
{
  const float* xs  = (const float*)d_in[0];
  const float* WQw = (const float*)d_in[1];
  const float* WQb = (const float*)d_in[2];
  const float* WKw = (const float*)d_in[3];
  const float* WKb = (const float*)d_in[4];
  const float* WVw = (const float*)d_in[5];
  const float* WVb = (const float*)d_in[6];

  const size_t ME = (size_t)BB * SS * EE;   // 8M tokens*dim
  const size_t WE = (size_t)EE * EE;        // 1M weight elems

  f16* Xh = (f16*)d_ws;
  f16* Wq = Xh + ME;
  f16* Wk = Wq + WE;
  f16* Wv = Wk + WE;
  f16* Qh = Wv + WE;
  f16* Kh = Qh + ME;
  f16* Vt = Kh + ME;
  f16* Sc = Vt + ME;   // BB*SS*SS f16 = 32 MiB

  // 1) casts (one launch): (8M + 3*1M)/4 = 2883584 f4 -> 11264 blocks exact
  cast_all_kernel<<<dim3(11264), 256, 0, stream>>>(
      xs, WQw, WKw, WVw, Xh, Wq, Wk, Wv);

  // 2) projections: 3-deep-ring 256x128 tiles; 768 blocks = exactly 3 CU rounds
  proj3_kernel<<<dim3(768), 512, 0, stream>>>(
      Xh, Wq, Wk, Wv, WQb, WKb, WVb, Qh, Kh, Vt);

  // 3) scores (lower-tri tiles)
  const int nTri = (SS / BM) * (SS / BM + 1) / 2;   // 136
  scores_kernel<<<dim3(nTri, 1, BB), 256, 0, stream>>>(Qh, Kh, Sc);

  // 4) softmax
  softmax_kernel<<<dim3(SS, BB), 256, 0, stream>>>(Sc);

  // 5) PV
  pv_kernel<<<dim3(512), 256, 0, stream>>>(Sc, Vt, (float*)d_out);
}